// Round 1
// baseline (352.481 us; speedup 1.0000x reference)
//
#include <hip/hip_runtime.h>
#include <cmath>

#define T_    128
#define F_    64
#define DI    512
#define DS    16
#define DTR   32
#define NSEQ  128   // b * num_nodes
#define NROW  16384 // NSEQ * T_

// workspace layout (float offsets)
#define U_OFF    0u
#define SRES_OFF 8388608u                 // NROW*DI
#define DPH_OFF  16777216u                // + NROW*DI
#define DPT_OFF  (DPH_OFF + NROW*32u)
#define B_OFF    (DPT_OFF + NROW)
#define C_OFF    (B_OFF + NROW*16u)
// total = C_OFF + NROW*16 = 17,842,176 floats (~71.4 MB)

__device__ __forceinline__ float silu_f(float v) {
    return v / (1.f + __expf(-v));
}

// K1: xz = X @ W_in, split into xc (conv4 + silu -> u) and res (silu -> sres)
// grid (4 colgroups, 128 seqs), 256 threads. Each thread owns one output column
// for the whole time axis: W_in column in registers, X row via uniform loads.
__global__ __launch_bounds__(256) void k1_inproj(
    const float* __restrict__ x, const float* __restrict__ W_in,
    const float* __restrict__ W_conv, const float* __restrict__ b_conv,
    float* __restrict__ u, float* __restrict__ sres)
{
    const int s = blockIdx.y;
    const int c = blockIdx.x * 256 + threadIdx.x;   // 0..1023
    float w[64];
#pragma unroll
    for (int f = 0; f < 64; ++f) w[f] = W_in[f * 1024 + c];
    const float* xs = x + (size_t)s * (T_ * F_);

    if (c < DI) {  // xc path: causal depthwise conv (k=4) + silu
        const float wc0 = W_conv[c*4+0], wc1 = W_conv[c*4+1];
        const float wc2 = W_conv[c*4+2], wc3 = W_conv[c*4+3];
        const float bc  = b_conv[c];
        float p1 = 0.f, p2 = 0.f, p3 = 0.f;   // xc[t-1], xc[t-2], xc[t-3]
        for (int t = 0; t < T_; ++t) {
            float acc = 0.f;
#pragma unroll
            for (int f = 0; f < 64; ++f) acc = fmaf(xs[t*F_ + f], w[f], acc);
            float pre = bc;
            pre = fmaf(wc0, p3, pre);
            pre = fmaf(wc1, p2, pre);
            pre = fmaf(wc2, p1, pre);
            pre = fmaf(wc3, acc, pre);
            p3 = p2; p2 = p1; p1 = acc;
            u[(size_t)(s*T_ + t)*DI + c] = silu_f(pre);
        }
    } else {       // res path: silu only
        const int d = c - DI;
        for (int t = 0; t < T_; ++t) {
            float acc = 0.f;
#pragma unroll
            for (int f = 0; f < 64; ++f) acc = fmaf(xs[t*F_ + f], w[f], acc);
            sres[(size_t)(s*T_ + t)*DI + d] = silu_f(acc);
        }
    }
}

// K2: per 16 rows: xdbl = u_row @ W_xproj (64 cols) -> dlt/B/C;
// delta = softplus(dlt @ W_dt + b_dt); delta_p via pad structure:
//   dpt[r] = sum_d delta ; dph[r][d<32] = S_tail + sum_j delta[j]*adj[j][d]
__global__ __launch_bounds__(256) void k2_xproj(
    const float* __restrict__ u, const float* __restrict__ W_xproj,
    const float* __restrict__ W_dt, const float* __restrict__ b_dt,
    const int* __restrict__ adj,
    float* __restrict__ dph, float* __restrict__ dpt,
    float* __restrict__ Bb, float* __restrict__ Cb)
{
    __shared__ float u_l[16][DI];      // 32KB
    __shared__ float xdbl_l[16][64];   // 4KB
    __shared__ float head_l[16][DTR];  // 2KB
    __shared__ float scrB[4][16][64];  // 16KB
    __shared__ float scrS[4][16];
    __shared__ float stail_l[16];

    const int tid = threadIdx.x;
    const int r0  = blockIdx.x * 16;

    // Phase A: stage 16 u rows
    {
        const float* src = u + (size_t)r0 * DI;
        float* dst = &u_l[0][0];
        for (int i = tid; i < 16*DI; i += 256) dst[i] = src[i];
    }
    __syncthreads();

    // Phase B: xdbl = u @ W_xproj. thread = (cc 0..63, i-chunk 0..3 of 128)
    {
        const int cc = tid & 63;
        const int ch = tid >> 6;
        float part[16];
#pragma unroll
        for (int r = 0; r < 16; ++r) part[r] = 0.f;
        const int i0 = ch * 128;
        for (int ii = 0; ii < 128; ii += 4) {
            const int i = i0 + ii;
            const float w0 = W_xproj[(i+0)*64 + cc];
            const float w1 = W_xproj[(i+1)*64 + cc];
            const float w2 = W_xproj[(i+2)*64 + cc];
            const float w3 = W_xproj[(i+3)*64 + cc];
#pragma unroll
            for (int r = 0; r < 16; ++r) {
                const float4 uv = *(const float4*)&u_l[r][i];
                part[r] = fmaf(uv.x, w0, part[r]);
                part[r] = fmaf(uv.y, w1, part[r]);
                part[r] = fmaf(uv.z, w2, part[r]);
                part[r] = fmaf(uv.w, w3, part[r]);
            }
        }
#pragma unroll
        for (int r = 0; r < 16; ++r) scrB[ch][r][cc] = part[r];
    }
    __syncthreads();
    // reduce chunks, write B,C to global, dlt stays in LDS
    for (int o = tid; o < 1024; o += 256) {
        const int r = o >> 6, cc = o & 63;
        const float v = scrB[0][r][cc] + scrB[1][r][cc] + scrB[2][r][cc] + scrB[3][r][cc];
        xdbl_l[r][cc] = v;
        if (cc >= 32) {
            if (cc < 48) Bb[(size_t)(r0 + r)*DS + (cc - 32)] = v;
            else         Cb[(size_t)(r0 + r)*DS + (cc - 48)] = v;
        }
    }
    __syncthreads();

    // Phase C: delta for d = tid and tid+256, all 16 rows; row sums via shuffles
    {
        float wdt0[32], wdt1[32];
#pragma unroll
        for (int j = 0; j < 32; ++j) {
            wdt0[j] = W_dt[j*DI + tid];
            wdt1[j] = W_dt[j*DI + tid + 256];
        }
        const float b0 = b_dt[tid], b1 = b_dt[tid + 256];
        float psum[16];
        float dhead[16];
#pragma unroll
        for (int r = 0; r < 16; ++r) {
            float a0 = b0, a1 = b1;
#pragma unroll
            for (int j = 0; j < 32; ++j) {
                const float dl = xdbl_l[r][j];
                a0 = fmaf(dl, wdt0[j], a0);
                a1 = fmaf(dl, wdt1[j], a1);
            }
            const float d0 = (a0 > 20.f) ? a0 : log1pf(__expf(a0));
            const float d1 = (a1 > 20.f) ? a1 : log1pf(__expf(a1));
            dhead[r] = d0;
            psum[r] = d0 + d1;
        }
        if (tid < 32) {
#pragma unroll
            for (int r = 0; r < 16; ++r) head_l[r][tid] = dhead[r];
        }
        const int lane = tid & 63, wv = tid >> 6;
#pragma unroll
        for (int r = 0; r < 16; ++r) {
            float v = psum[r];
#pragma unroll
            for (int off = 32; off > 0; off >>= 1) v += __shfl_down(v, off, 64);
            if (lane == 0) scrS[wv][r] = v;
        }
    }
    __syncthreads();
    if (tid < 16) {
        const int r = tid;
        const float stot = scrS[0][r] + scrS[1][r] + scrS[2][r] + scrS[3][r];
        float sh = 0.f;
#pragma unroll
        for (int j = 0; j < 32; ++j) sh += head_l[r][j];
        stail_l[r] = stot - sh;
        dpt[r0 + r] = stot;
    }
    __syncthreads();

    // Phase E: dph[r][d] = S_tail + sum_j delta_head[j] * adj[j][d]
    for (int o = tid; o < 512; o += 256) {
        const int r = o >> 5, d = o & 31;
        float acc = stail_l[r];
#pragma unroll
        for (int j = 0; j < 32; ++j)
            acc = fmaf(head_l[r][j], (float)adj[j*32 + d], acc);
        dph[(size_t)(r0 + r)*32 + d] = acc;
    }
}

// K3: selective scan. grid (2 ch-halves, 128 seqs), 256 threads, 1 channel/thread.
// h[16] in registers; reads sres and overwrites it with the gated y (yfull).
__global__ __launch_bounds__(256) void k3_scan(
    const float* __restrict__ u, float* sres_y,
    const float* __restrict__ dph, const float* __restrict__ dpt,
    const float* __restrict__ Bb, const float* __restrict__ Cb,
    const float* __restrict__ A_log, const float* __restrict__ Dvec)
{
    const int s = blockIdx.y;
    const int d = blockIdx.x * 256 + threadIdx.x;
    float A[DS];
#pragma unroll
    for (int n = 0; n < DS; ++n) A[n] = -__expf(A_log[d*DS + n]);
    const float Dd = Dvec[d];
    float h[DS];
#pragma unroll
    for (int n = 0; n < DS; ++n) h[n] = 0.f;
    const bool isHead = (d < 32);
    for (int t = 0; t < T_; ++t) {
        const int r = s*T_ + t;
        float dp;
        if (isHead) dp = dph[(size_t)r*32 + d];
        else        dp = dpt[r];
        const float uv = u[(size_t)r*DI + d];
        const float du = dp * uv;
        float y = 0.f;
#pragma unroll
        for (int n = 0; n < DS; ++n) {
            const float dA = __expf(dp * A[n]);
            h[n] = fmaf(dA, h[n], du * Bb[(size_t)r*DS + n]);
            y = fmaf(h[n], Cb[(size_t)r*DS + n], y);
        }
        const float yf = (y + uv * Dd) * sres_y[(size_t)r*DI + d];
        sres_y[(size_t)r*DI + d] = yf;
    }
}

// K4: out = yfull @ W_out. grid 256 blocks x 64 rows; W_out staged in LDS.
__global__ __launch_bounds__(256) void k4_out(
    const float* __restrict__ y, const float* __restrict__ W_out,
    float* __restrict__ out)
{
    __shared__ float w_l[DI*64];     // 128KB
    __shared__ float y_l[4][DI];     // 8KB
    __shared__ float scr[4][4][64];  // 4KB
    const int tid = threadIdx.x;
    for (int i = tid; i < DI*64; i += 256) w_l[i] = W_out[i];
    const int r0 = blockIdx.x * 64;
    const int cc = tid & 63;
    const int ch = tid >> 6;
    for (int rb = 0; rb < 64; rb += 4) {
        __syncthreads();   // w_l ready (iter 0); y_l/scr safe to overwrite
        for (int i = tid; i < 4*DI; i += 256)
            y_l[i >> 9][i & 511] = y[(size_t)(r0 + rb)*DI + i];
        __syncthreads();
        float p0=0.f, p1=0.f, p2=0.f, p3=0.f;
        for (int ii = 0; ii < 128; ++ii) {
            const int i = ch*128 + ii;
            const float w = w_l[i*64 + cc];
            p0 = fmaf(y_l[0][i], w, p0);
            p1 = fmaf(y_l[1][i], w, p1);
            p2 = fmaf(y_l[2][i], w, p2);
            p3 = fmaf(y_l[3][i], w, p3);
        }
        scr[ch][0][cc]=p0; scr[ch][1][cc]=p1; scr[ch][2][cc]=p2; scr[ch][3][cc]=p3;
        __syncthreads();
        {
            const int rr = tid >> 6, c2 = tid & 63;
            const float v = scr[0][rr][c2] + scr[1][rr][c2]
                          + scr[2][rr][c2] + scr[3][rr][c2];
            out[(size_t)(r0 + rb + rr)*64 + c2] = v;
        }
    }
}

extern "C" void kernel_launch(void* const* d_in, const int* in_sizes, int n_in,
                              void* d_out, int out_size, void* d_ws, size_t ws_size,
                              hipStream_t stream)
{
    const float* x      = (const float*)d_in[0];
    const int*   adj    = (const int*)  d_in[1];
    const float* W_in   = (const float*)d_in[2];
    const float* W_conv = (const float*)d_in[3];
    const float* b_conv = (const float*)d_in[4];
    const float* W_xp   = (const float*)d_in[5];
    const float* W_dt   = (const float*)d_in[6];
    const float* b_dt   = (const float*)d_in[7];
    const float* A_log  = (const float*)d_in[8];
    const float* Dvec   = (const float*)d_in[9];
    const float* W_out  = (const float*)d_in[10];

    float* ws   = (float*)d_ws;
    float* u    = ws + U_OFF;
    float* sres = ws + SRES_OFF;   // reused as yfull by k3
    float* dph  = ws + DPH_OFF;
    float* dpt  = ws + DPT_OFF;
    float* Bb   = ws + B_OFF;
    float* Cb   = ws + C_OFF;
    float* out  = (float*)d_out;

    k1_inproj<<<dim3(4, 128), 256, 0, stream>>>(x, W_in, W_conv, b_conv, u, sres);
    k2_xproj <<<dim3(1024),   256, 0, stream>>>(u, W_xp, W_dt, b_dt, adj, dph, dpt, Bb, Cb);
    k3_scan  <<<dim3(2, 128), 256, 0, stream>>>(u, sres, dph, dpt, Bb, Cb, A_log, Dvec);
    k4_out   <<<dim3(256),    256, 0, stream>>>(sres, W_out, out);
}